// Round 10
// baseline (322.102 us; speedup 1.0000x reference)
//
#include <hip/hip_runtime.h>
#include <stdint.h>

#define BB   2
#define SS   2048
#define DD   1024
#define HH   16
#define DKK  64
#define MM   (BB*SS)   // 4096 rows total

typedef __attribute__((ext_vector_type(4))) float f32x4;
typedef __attribute__((ext_vector_type(8))) short s16x8;

#define MFMA_B16(a, b, c) __builtin_amdgcn_mfma_f32_16x16x32_bf16((a), (b), (c), 0, 0, 0)

__device__ __forceinline__ ushort f2bf(float f) {
  uint u = __float_as_uint(f);
  u += 0x7FFFu + ((u >> 16) & 1u);   // round-to-nearest-even
  return (ushort)(u >> 16);
}
__device__ __forceinline__ float bf2f(ushort u) {
  return __uint_as_float((uint)u << 16);
}
__device__ __forceinline__ s16x8 cvt8(const float* src) {
  float4 a = *(const float4*)src, b = *(const float4*)(src + 4);
  union { ushort u[8]; s16x8 v; } r;
  r.u[0] = f2bf(a.x); r.u[1] = f2bf(a.y); r.u[2] = f2bf(a.z); r.u[3] = f2bf(a.w);
  r.u[4] = f2bf(b.x); r.u[5] = f2bf(b.y); r.u[6] = f2bf(b.z); r.u[7] = f2bf(b.w);
  return r.v;
}

// ---------------- Y = A @ W^T  (A:[4096,1024], W fp32 [1024,1024]) ----------------
// AF32: A is fp32 (converted to bf16 during staging); else A is bf16.
// mode 0: Q-proj -> [B,H,S,DK] bf16, scaled by 1/8
// mode 1: K-proj -> [B,H,S,DK] bf16
// mode 2: V-proj -> [B,H,DK,S] bf16 (transposed)
// mode 3: O-proj -> [4096,1024] fp32 (d_out)
template<int AF32>
__global__ __launch_bounds__(256, 2) void proj_gemm(
    const void* __restrict__ Ap, const float* __restrict__ W,
    void* __restrict__ outp, int mode)
{
  __shared__ ushort As[128 * 32];
  __shared__ ushort Bs[128 * 32];
  const int tid  = threadIdx.x;
  const int lane = tid & 63, wave = tid >> 6;
  const int q = lane & 15, g = lane >> 4;
  const int wr = wave >> 1, wc = wave & 1;
  const int mblk = blockIdx.x * 128, nblk = blockIdx.y * 128;

  f32x4 acc[4][4];
  {
    f32x4 z = {0.f, 0.f, 0.f, 0.f};
#pragma unroll
    for (int i = 0; i < 4; ++i)
#pragma unroll
      for (int j = 0; j < 4; ++j) acc[i][j] = z;
  }

  const int r0 = tid >> 2;            // staging row
  const int e0 = (tid & 3) * 8;       // staging element offset within row
  for (int k0 = 0; k0 < 1024; k0 += 32) {
#pragma unroll
    for (int it = 0; it < 2; ++it) {
      const int row = r0 + it * 64;
      if (AF32) {
        *(s16x8*)&As[row * 32 + e0] =
            cvt8((const float*)Ap + (size_t)(mblk + row) * 1024 + k0 + e0);
      } else {
        *(s16x8*)&As[row * 32 + e0] =
            *(const s16x8*)((const ushort*)Ap + (size_t)(mblk + row) * 1024 + k0 + e0);
      }
      *(s16x8*)&Bs[row * 32 + e0] =
          cvt8(W + (size_t)(nblk + row) * 1024 + k0 + e0);
    }
    __syncthreads();
    s16x8 af[4], bf[4];
#pragma unroll
    for (int t = 0; t < 4; ++t) {
      af[t] = *(const s16x8*)&As[(wr * 64 + t * 16 + q) * 32 + g * 8];
      bf[t] = *(const s16x8*)&Bs[(wc * 64 + t * 16 + q) * 32 + g * 8];
    }
#pragma unroll
    for (int mt = 0; mt < 4; ++mt)
#pragma unroll
      for (int nt = 0; nt < 4; ++nt)
        acc[mt][nt] = MFMA_B16(af[mt], bf[nt], acc[mt][nt]);
    __syncthreads();
  }

  // epilogue: C layout col = lane&15 (N), row = (lane>>4)*4 + j (M)
  if (mode == 3) {
    float* O = (float*)outp;
#pragma unroll
    for (int mt = 0; mt < 4; ++mt)
#pragma unroll
      for (int nt = 0; nt < 4; ++nt)
#pragma unroll
        for (int j = 0; j < 4; ++j) {
          const int s = mblk + wr * 64 + mt * 16 + g * 4 + j;
          const int o = nblk + wc * 64 + nt * 16 + q;
          O[(size_t)s * DD + o] = acc[mt][nt][j];
        }
  } else if (mode == 2) {
    ushort* Vt = (ushort*)outp;
#pragma unroll
    for (int mt = 0; mt < 4; ++mt)
#pragma unroll
      for (int nt = 0; nt < 4; ++nt) {
        const int s0 = mblk + wr * 64 + mt * 16 + g * 4;
        const int o  = nblk + wc * 64 + nt * 16 + q;
        const int h = o >> 6, dk = o & 63;
        const int b = s0 >> 11, sr = s0 & 2047;
        ushort4 pk;
        pk.x = f2bf(acc[mt][nt][0]); pk.y = f2bf(acc[mt][nt][1]);
        pk.z = f2bf(acc[mt][nt][2]); pk.w = f2bf(acc[mt][nt][3]);
        *(ushort4*)(Vt + ((size_t)((b * 16 + h) * 64 + dk)) * SS + sr) = pk;
      }
  } else {
    // Q/K proj: LDS-staged epilogue -> full-row contiguous 16B/lane stores.
    const float scale = (mode == 0) ? 0.125f : 1.0f;
    ushort* P = (ushort*)outp;
    ushort* wl = As + wave * 1024;   // 2KB wave-private staging (reuse As)
    const int h0 = (nblk + wc * 64) >> 6;
#pragma unroll
    for (int mt = 0; mt < 4; ++mt) {
      const int s0 = mblk + wr * 64 + mt * 16;
      const int b  = s0 >> 11, sr0 = s0 & 2047;
#pragma unroll
      for (int nt = 0; nt < 4; ++nt)
#pragma unroll
        for (int j = 0; j < 4; ++j)
          wl[(g * 4 + j) * 64 + nt * 16 + q] = f2bf(acc[mt][nt][j] * scale);
      // same-wave LDS write->read: compiler inserts lgkmcnt wait
#pragma unroll
      for (int it = 0; it < 2; ++it) {
        s16x8 v = *(const s16x8*)((char*)wl + it * 1024 + lane * 16);
        const int lr = it * 8 + (lane >> 3);
        const int c  = (lane & 7) * 8;
        *(s16x8*)(P + ((size_t)((b * 16 + h0) * SS) + sr0 + lr) * DKK + c) = v;
      }
    }
  }
}

// ---------------- pass 1: rden[b][q][k] = 1/sum_h exp(s) — GEMM-shaped ----------------
__global__ __launch_bounds__(256, 2) void den_kernel(
    const ushort* __restrict__ Qp, const ushort* __restrict__ Kp,
    ushort* __restrict__ Rden)
{
  __shared__ ushort smem[16384];        // 32 KB: staging 16 KB / bounce 32 KB (reused)
  ushort* As = smem;                    // K-tile [128][32]
  ushort* Bs = smem + 4096;             // Q-tile [128][32]
  const int tid  = threadIdx.x;
  const int lane = tid & 63, wave = tid >> 6;
  const int q = lane & 15, g = lane >> 4;
  const int wr = wave >> 1, wc = wave & 1;
  const int kblk = blockIdx.x * 128, qblk = blockIdx.y * 128;
  const int b = blockIdx.z;

  f32x4 den[4][4];
  {
    f32x4 z = {0.f, 0.f, 0.f, 0.f};
#pragma unroll
    for (int i = 0; i < 4; ++i)
#pragma unroll
      for (int j = 0; j < 4; ++j) den[i][j] = z;
  }

  const int r0 = tid >> 2;
  const int e0 = (tid & 3) * 8;
  for (int h = 0; h < 16; ++h) {
    const ushort* Kh = Kp + ((size_t)(b * 16 + h) * SS + kblk) * DKK;
    const ushort* Qh = Qp + ((size_t)(b * 16 + h) * SS + qblk) * DKK;
    f32x4 acc[4][4];
    {
      f32x4 z = {0.f, 0.f, 0.f, 0.f};
#pragma unroll
      for (int i = 0; i < 4; ++i)
#pragma unroll
        for (int j = 0; j < 4; ++j) acc[i][j] = z;
    }
#pragma unroll
    for (int dh = 0; dh < 2; ++dh) {
      const int d0 = dh * 32;
#pragma unroll
      for (int it = 0; it < 2; ++it) {
        const int row = r0 + it * 64;
        *(s16x8*)&As[row * 32 + e0] = *(const s16x8*)(Kh + (size_t)row * DKK + d0 + e0);
        *(s16x8*)&Bs[row * 32 + e0] = *(const s16x8*)(Qh + (size_t)row * DKK + d0 + e0);
      }
      __syncthreads();
      s16x8 af[4], bf[4];
#pragma unroll
      for (int t = 0; t < 4; ++t) {
        af[t] = *(const s16x8*)&As[(wr * 64 + t * 16 + q) * 32 + g * 8];
        bf[t] = *(const s16x8*)&Bs[(wc * 64 + t * 16 + q) * 32 + g * 8];
      }
#pragma unroll
      for (int mt = 0; mt < 4; ++mt)
#pragma unroll
        for (int nt = 0; nt < 4; ++nt)
          acc[mt][nt] = MFMA_B16(af[mt], bf[nt], acc[mt][nt]);
      __syncthreads();
    }
#pragma unroll
    for (int mt = 0; mt < 4; ++mt)
#pragma unroll
      for (int nt = 0; nt < 4; ++nt)
#pragma unroll
        for (int r = 0; r < 4; ++r)
          den[mt][nt][r] += __expf(acc[mt][nt][r]);
  }

  // epilogue: transpose 64k x 64q wave tile -> rden[q][k] via swizzled LDS.
  char* aw2 = (char*)smem + wave * 8192;   // 8 KB wave-private
#pragma unroll
  for (int mt = 0; mt < 4; ++mt)
#pragma unroll
    for (int nt = 0; nt < 4; ++nt) {
      const int ql = nt * 16 + q;           // q_local within wave tile
      ushort4 pk;
      pk.x = f2bf(1.0f / den[mt][nt][0]);
      pk.y = f2bf(1.0f / den[mt][nt][1]);
      pk.z = f2bf(1.0f / den[mt][nt][2]);
      pk.w = f2bf(1.0f / den[mt][nt][3]);   // k_local = mt*16+g*4 + 0..3
      *(ushort4*)(aw2 + ql * 128 + ((mt * 32 + g * 8) ^ ((ql & 7) << 4))) = pk;
    }
  // same-wave LDS write->read (lgkmcnt auto), then coalesced stores
#pragma unroll
  for (int it = 0; it < 8; ++it) {
    const int idx = it * 64 + lane;
    const int row = idx >> 3;               // q_local 0..63
    const int seg = idx & 7;                // 16B segment of k
    s16x8 v = *(const s16x8*)(aw2 + row * 128 + ((seg * 16) ^ ((row & 7) << 4)));
    *(s16x8*)(Rden + (size_t)b * SS * SS
              + (size_t)(qblk + wc * 64 + row) * SS
              + kblk + wr * 64 + seg * 8) = v;
  }
}

// ---------------- pass 2: block-tiled attention, 8 waves ----------------
// grid 512: bid = qt*32 + bh, bh = b*16+h.  bid%8 pins (b,h) K/V per XCD L2.
// Block = (b, h, 128 q-rows); 8 waves x 16 q-rows.  32 phases x 64 keys:
// stage K[64k][64d] + V^T[64dk][64k] in XOR-swizzled shared LDS; rden rows
// staged per-wave (no cross-wave reuse -> wave-private, no barrier, coalesced
// 16B/lane loads).  barrier, QK->exp*rden->P(wave LDS)->PV, barrier.
// 16 waves/CU (2 blocks) vs R9's 8 -> stage/compute of sibling blocks overlap.
__global__ __launch_bounds__(512, 2) void attn4_kernel(
    const ushort* __restrict__ Qp, const ushort* __restrict__ Kp,
    const ushort* __restrict__ Vt, const ushort* __restrict__ Rden,
    ushort* __restrict__ Ctx)
{
  __shared__ ushort Ktile[64 * 64];      //  8 KB, row k (swz by k&7)
  __shared__ ushort Vtile[64 * 64];      //  8 KB, row dk (swz by dk&7)
  __shared__ ushort Rw_all[8][16 * 64];  // 16 KB, per-wave rden rows (swz)
  __shared__ ushort aw_all[8][16 * 64];  // 16 KB, per-wave P / epilogue

  const int tid  = threadIdx.x;
  const int lane = tid & 63;
  const int w    = tid >> 6;             // wave 0..7
  const int q    = lane & 15;
  const int g    = lane >> 4;
  const int bid  = blockIdx.x;
  const int bh   = bid & 31;
  const int b    = bh >> 4, h = bh & 15;
  const int qblk = (bid >> 5) * 128;

  // hoist Q fragment (B-operand: col=lane&15 -> q-row, dk contiguous per g)
  const ushort* Qb = Qp + ((size_t)bh * SS + qblk + w * 16 + q) * DKK + g * 8;
  s16x8 qf0 = *(const s16x8*)(Qb);
  s16x8 qf1 = *(const s16x8*)(Qb + 32);

  const ushort* Ks = Kp + (size_t)bh * SS * DKK;        // K rows contiguous
  const ushort* Vs = Vt + (size_t)bh * DKK * SS;        // V^T rows stride SS
  const ushort* Rs = Rden + (size_t)b * SS * SS + (size_t)(qblk + w * 16) * SS;

  f32x4 acc[4];
  {
    f32x4 z = {0.f, 0.f, 0.f, 0.f};
#pragma unroll
    for (int n = 0; n < 4; ++n) acc[n] = z;
  }

  ushort* Rw = Rw_all[w];
  ushort* aw = aw_all[w];
  const int srow = tid >> 3, sseg = tid & 7;            // K/V staging coords
  const int sd   = (sseg * 8) ^ ((srow & 7) << 3);
  const int r16  = lane >> 2;                           // R staging row 0..15
  const int sgA  = (lane & 3) * 2;                      // R staging 8u-block base

  for (int kt = 0; kt < 32; ++kt) {
    const int k0 = kt * 64;
    // ---- stage K (contiguous 8KB) + V^T (64 rows x 128B), 16B/thread each
    *(s16x8*)&Ktile[srow * 64 + sd] = *(const s16x8*)(Ks + (size_t)k0 * DKK + tid * 8);
    *(s16x8*)&Vtile[srow * 64 + sd] = *(const s16x8*)(Vs + (size_t)srow * SS + k0 + sseg * 8);
    // ---- stage wave's 16 rden rows (same-wave write->read, no barrier)
#pragma unroll
    for (int it = 0; it < 2; ++it) {
      const int sb = sgA + it;   // 8-ushort block 0..7
      *(s16x8*)&Rw[r16 * 64 + ((sb * 8) ^ ((r16 & 7) << 3))] =
          *(const s16x8*)(Rs + (size_t)r16 * SS + k0 + sb * 8);
    }
    __syncthreads();

    // ---- QK scores -> exp * rden -> P into wave-private aw
#pragma unroll
    for (int ks = 0; ks < 4; ++ks) {
      const int kr = ks * 16 + q;
      s16x8 a0 = *(const s16x8*)&Ktile[kr * 64 + ((g * 8) ^ ((kr & 7) << 3))];
      s16x8 a1 = *(const s16x8*)&Ktile[kr * 64 + ((32 + g * 8) ^ ((kr & 7) << 3))];
      f32x4 c = {0.f, 0.f, 0.f, 0.f};
      c = MFMA_B16(a0, qf0, c);
      c = MFMA_B16(a1, qf1, c);
      // rden[q][ks*16+g*4 .. +3] from swizzled Rw
      ushort4 rv = *(const ushort4*)&Rw[q * 64 + (((ks * 2 + (g >> 1)) ^ (q & 7)) * 8) + (g & 1) * 4];
      uint2 pp;
      pp.x = (uint)f2bf(__expf(c[0]) * bf2f(rv.x)) |
             ((uint)f2bf(__expf(c[1]) * bf2f(rv.y)) << 16);
      pp.y = (uint)f2bf(__expf(c[2]) * bf2f(rv.z)) |
             ((uint)f2bf(__expf(c[3]) * bf2f(rv.w)) << 16);
      *(uint2*)&aw[q * 64 + ((ks * 16 + g * 4) ^ ((q & 7) << 3))] = pp;
    }
    // ---- PV over the 64-key tile (same-wave aw; lgkmcnt auto)
#pragma unroll
    for (int kc = 0; kc < 2; ++kc) {
      s16x8 vf[4];
#pragma unroll
      for (int n = 0; n < 4; ++n) {
        const int vr = n * 16 + q;
        vf[n] = *(const s16x8*)&Vtile[vr * 64 + ((kc * 32 + g * 8) ^ ((vr & 7) << 3))];
      }
      s16x8 pa = *(const s16x8*)&aw[q * 64 + ((kc * 32 + g * 8) ^ ((q & 7) << 3))];
#pragma unroll
      for (int n = 0; n < 4; ++n)
        acc[n] = MFMA_B16(pa, vf[n], acc[n]);
    }
    __syncthreads();
  }

  // epilogue: stage 16 rows x 64 cols in wave-private aw, then coalesced
  // 16B/lane stores (each instr: 8 rows x 128B contiguous).
#pragma unroll
  for (int n = 0; n < 4; ++n)
#pragma unroll
    for (int j = 0; j < 4; ++j)
      aw[(g * 4 + j) * 64 + n * 16 + q] = f2bf(acc[n][j]);
  ushort* P = Ctx + ((size_t)(b * SS) + qblk + w * 16) * DD + h * 64;
#pragma unroll
  for (int it = 0; it < 2; ++it) {
    const int idx = it * 64 + lane;
    const int row = idx >> 3;
    const int seg = idx & 7;
    s16x8 v = *(const s16x8*)&aw[row * 64 + seg * 8];
    *(s16x8*)(P + (size_t)row * DD + seg * 8) = v;
  }
}

extern "C" void kernel_launch(void* const* d_in, const int* in_sizes, int n_in,
                              void* d_out, int out_size, void* d_ws, size_t ws_size,
                              hipStream_t stream) {
  const float* Query = (const float*)d_in[0];
  const float* Key   = (const float*)d_in[1];
  const float* Value = (const float*)d_in[2];
  const float* Wq    = (const float*)d_in[3];
  const float* Wk    = (const float*)d_in[4];
  const float* Wv    = (const float*)d_in[5];
  const float* Wo    = (const float*)d_in[6];

  size_t off = 0;
  char* ws = (char*)d_ws;
  auto alloc = [&](size_t bytes) -> void* {
    void* p = ws + off;
    off += (bytes + 255) & ~(size_t)255;
    return p;
  };
  const size_t nX = (size_t)MM * DD;       // 4194304
  const size_t nS = (size_t)BB * SS * SS;  // 8388608
  ushort* Qp   = (ushort*)alloc(nX * 2);
  ushort* Kp   = (ushort*)alloc(nX * 2);
  ushort* Vtb  = (ushort*)alloc(nX * 2);
  ushort* Rden = (ushort*)alloc(nS * 2);   // bf16 1/den, 16.7 MB
  ushort* Ctx  = (ushort*)alloc(nX * 2);

  dim3 pg(32, 8), pb(256);
  proj_gemm<1><<<pg, pb, 0, stream>>>(Query, Wq, Qp, 0);
  proj_gemm<1><<<pg, pb, 0, stream>>>(Key,   Wk, Kp, 1);
  proj_gemm<1><<<pg, pb, 0, stream>>>(Value, Wv, Vtb, 2);

  den_kernel<<<dim3(16, 16, 2), 256, 0, stream>>>(Qp, Kp, Rden);
  attn4_kernel<<<512, 512, 0, stream>>>(Qp, Kp, Vtb, Rden, Ctx);

  proj_gemm<0><<<pg, pb, 0, stream>>>(Ctx, Wo, d_out, 3);
}

// Round 11
// 187.981 us; speedup vs baseline: 1.7135x; 1.7135x over previous
//
#include <hip/hip_runtime.h>
#include <stdint.h>

#define BB   2
#define SS   2048
#define DD   1024
#define HH   16
#define DKK  64
#define MM   (BB*SS)   // 4096 rows total

typedef __attribute__((ext_vector_type(4))) float f32x4;
typedef __attribute__((ext_vector_type(8))) short s16x8;

#define MFMA_B16(a, b, c) __builtin_amdgcn_mfma_f32_16x16x32_bf16((a), (b), (c), 0, 0, 0)

__device__ __forceinline__ ushort f2bf(float f) {
  uint u = __float_as_uint(f);
  u += 0x7FFFu + ((u >> 16) & 1u);   // round-to-nearest-even
  return (ushort)(u >> 16);
}
__device__ __forceinline__ float bf2f(ushort u) {
  return __uint_as_float((uint)u << 16);
}
__device__ __forceinline__ s16x8 cvt8(const float* src) {
  float4 a = *(const float4*)src, b = *(const float4*)(src + 4);
  union { ushort u[8]; s16x8 v; } r;
  r.u[0] = f2bf(a.x); r.u[1] = f2bf(a.y); r.u[2] = f2bf(a.z); r.u[3] = f2bf(a.w);
  r.u[4] = f2bf(b.x); r.u[5] = f2bf(b.y); r.u[6] = f2bf(b.z); r.u[7] = f2bf(b.w);
  return r.v;
}

// ---------------- fp32 -> bf16 convert (8 elems/thread) — weights only ----------------
__global__ void cvt_kernel(const float* __restrict__ src, ushort* __restrict__ dst, int n) {
  int i = (blockIdx.x * 256 + threadIdx.x) * 8;
  if (i >= n) return;
  *(s16x8*)(dst + i) = cvt8(src + i);
}

// ---------------- fused Q/K/V projection: z selects proj ----------------
// grid (32 mblk, 8 nblk, 3 proj) = 768 blocks -> 3 blocks/CU co-resident:
// cross-block TLP hides the fp32 A-load + cvt latency that made the 1-block/CU
// version 81 us (R10 post-mortem).  A fp32 converted during staging; W bf16
// (pre-converted once — re-reading fp32 W 32x per block was waste).
// z=0: Q-proj -> [B,H,S,DK] bf16 scaled 1/8; z=1: K-proj same layout;
// z=2: V-proj -> [B,H,DK,S] bf16 transposed.
__global__ __launch_bounds__(256, 2) void qkv_proj(
    const float* __restrict__ Ia, const float* __restrict__ Ib, const float* __restrict__ Ic,
    const ushort* __restrict__ Wa, const ushort* __restrict__ Wb, const ushort* __restrict__ Wc,
    ushort* __restrict__ Oa, ushort* __restrict__ Ob, ushort* __restrict__ Oc)
{
  __shared__ ushort As[128 * 32];
  __shared__ ushort Bs[128 * 32];
  const int tid  = threadIdx.x;
  const int lane = tid & 63, wave = tid >> 6;
  const int q = lane & 15, g = lane >> 4;
  const int wr = wave >> 1, wc = wave & 1;
  const int mblk = blockIdx.x * 128, nblk = blockIdx.y * 128;
  const int mode = blockIdx.z;

  const float*  A = (mode == 0) ? Ia : (mode == 1) ? Ib : Ic;
  const ushort* W = (mode == 0) ? Wa : (mode == 1) ? Wb : Wc;

  f32x4 acc[4][4];
  {
    f32x4 z = {0.f, 0.f, 0.f, 0.f};
#pragma unroll
    for (int i = 0; i < 4; ++i)
#pragma unroll
      for (int j = 0; j < 4; ++j) acc[i][j] = z;
  }

  const int r0 = tid >> 2;            // staging row
  const int e0 = (tid & 3) * 8;       // staging element offset within row
  for (int k0 = 0; k0 < 1024; k0 += 32) {
#pragma unroll
    for (int it = 0; it < 2; ++it) {
      const int row = r0 + it * 64;
      *(s16x8*)&As[row * 32 + e0] = cvt8(A + (size_t)(mblk + row) * 1024 + k0 + e0);
      *(s16x8*)&Bs[row * 32 + e0] = *(const s16x8*)(W + (size_t)(nblk + row) * 1024 + k0 + e0);
    }
    __syncthreads();
    s16x8 af[4], bf[4];
#pragma unroll
    for (int t = 0; t < 4; ++t) {
      af[t] = *(const s16x8*)&As[(wr * 64 + t * 16 + q) * 32 + g * 8];
      bf[t] = *(const s16x8*)&Bs[(wc * 64 + t * 16 + q) * 32 + g * 8];
    }
#pragma unroll
    for (int mt = 0; mt < 4; ++mt)
#pragma unroll
      for (int nt = 0; nt < 4; ++nt)
        acc[mt][nt] = MFMA_B16(af[mt], bf[nt], acc[mt][nt]);
    __syncthreads();
  }

  // epilogue (C layout: col = lane&15 (N), row = (lane>>4)*4 + j (M))
  if (mode == 2) {
    ushort* Vt = Oc;
#pragma unroll
    for (int mt = 0; mt < 4; ++mt)
#pragma unroll
      for (int nt = 0; nt < 4; ++nt) {
        const int s0 = mblk + wr * 64 + mt * 16 + g * 4;
        const int o  = nblk + wc * 64 + nt * 16 + q;
        const int h = o >> 6, dk = o & 63;
        const int b = s0 >> 11, sr = s0 & 2047;
        ushort4 pk;
        pk.x = f2bf(acc[mt][nt][0]); pk.y = f2bf(acc[mt][nt][1]);
        pk.z = f2bf(acc[mt][nt][2]); pk.w = f2bf(acc[mt][nt][3]);
        *(ushort4*)(Vt + ((size_t)((b * 16 + h) * 64 + dk)) * SS + sr) = pk;
      }
  } else {
    // Q/K: LDS-staged epilogue -> full-row contiguous 16B/lane stores.
    const float scale = (mode == 0) ? 0.125f : 1.0f;
    ushort* P = (mode == 0) ? Oa : Ob;
    ushort* wl = As + wave * 1024;   // 2KB wave-private staging (reuse As)
    const int h0 = (nblk + wc * 64) >> 6;
#pragma unroll
    for (int mt = 0; mt < 4; ++mt) {
      const int s0 = mblk + wr * 64 + mt * 16;
      const int b  = s0 >> 11, sr0 = s0 & 2047;
#pragma unroll
      for (int nt = 0; nt < 4; ++nt)
#pragma unroll
        for (int j = 0; j < 4; ++j)
          wl[(g * 4 + j) * 64 + nt * 16 + q] = f2bf(acc[mt][nt][j] * scale);
      // same-wave LDS write->read: compiler inserts lgkmcnt wait
#pragma unroll
      for (int it = 0; it < 2; ++it) {
        s16x8 v = *(const s16x8*)((char*)wl + it * 1024 + lane * 16);
        const int lr = it * 8 + (lane >> 3);
        const int c  = (lane & 7) * 8;
        *(s16x8*)(P + ((size_t)((b * 16 + h0) * SS) + sr0 + lr) * DKK + c) = v;
      }
    }
  }
}

// ---------------- O-projection: Y = Ctx @ Wo^T -> fp32 d_out ----------------
__global__ __launch_bounds__(256, 2) void o_proj(
    const ushort* __restrict__ A, const ushort* __restrict__ W,
    float* __restrict__ O)
{
  __shared__ ushort As[128 * 32];
  __shared__ ushort Bs[128 * 32];
  const int tid  = threadIdx.x;
  const int lane = tid & 63, wave = tid >> 6;
  const int q = lane & 15, g = lane >> 4;
  const int wr = wave >> 1, wc = wave & 1;
  const int mblk = blockIdx.x * 128, nblk = blockIdx.y * 128;

  f32x4 acc[4][4];
  {
    f32x4 z = {0.f, 0.f, 0.f, 0.f};
#pragma unroll
    for (int i = 0; i < 4; ++i)
#pragma unroll
      for (int j = 0; j < 4; ++j) acc[i][j] = z;
  }

  const int r0 = tid >> 2;
  const int e0 = (tid & 3) * 8;
  for (int k0 = 0; k0 < 1024; k0 += 32) {
#pragma unroll
    for (int it = 0; it < 2; ++it) {
      const int row = r0 + it * 64;
      *(s16x8*)&As[row * 32 + e0] = *(const s16x8*)(A + (size_t)(mblk + row) * 1024 + k0 + e0);
      *(s16x8*)&Bs[row * 32 + e0] = *(const s16x8*)(W + (size_t)(nblk + row) * 1024 + k0 + e0);
    }
    __syncthreads();
    s16x8 af[4], bf[4];
#pragma unroll
    for (int t = 0; t < 4; ++t) {
      af[t] = *(const s16x8*)&As[(wr * 64 + t * 16 + q) * 32 + g * 8];
      bf[t] = *(const s16x8*)&Bs[(wc * 64 + t * 16 + q) * 32 + g * 8];
    }
#pragma unroll
    for (int mt = 0; mt < 4; ++mt)
#pragma unroll
      for (int nt = 0; nt < 4; ++nt)
        acc[mt][nt] = MFMA_B16(af[mt], bf[nt], acc[mt][nt]);
    __syncthreads();
  }

#pragma unroll
  for (int mt = 0; mt < 4; ++mt)
#pragma unroll
    for (int nt = 0; nt < 4; ++nt)
#pragma unroll
      for (int j = 0; j < 4; ++j) {
        const int s = mblk + wr * 64 + mt * 16 + g * 4 + j;
        const int o = nblk + wc * 64 + nt * 16 + q;
        O[(size_t)s * DD + o] = acc[mt][nt][j];
      }
}

// ---------------- pass 1: rden[b][q][k] = 1/sum_h exp(s) — GEMM-shaped ----------------
__global__ __launch_bounds__(256, 2) void den_kernel(
    const ushort* __restrict__ Qp, const ushort* __restrict__ Kp,
    ushort* __restrict__ Rden)
{
  __shared__ ushort smem[16384];        // 32 KB: staging 16 KB / bounce 32 KB (reused)
  ushort* As = smem;                    // K-tile [128][32]
  ushort* Bs = smem + 4096;             // Q-tile [128][32]
  const int tid  = threadIdx.x;
  const int lane = tid & 63, wave = tid >> 6;
  const int q = lane & 15, g = lane >> 4;
  const int wr = wave >> 1, wc = wave & 1;
  const int kblk = blockIdx.x * 128, qblk = blockIdx.y * 128;
  const int b = blockIdx.z;

  f32x4 den[4][4];
  {
    f32x4 z = {0.f, 0.f, 0.f, 0.f};
#pragma unroll
    for (int i = 0; i < 4; ++i)
#pragma unroll
      for (int j = 0; j < 4; ++j) den[i][j] = z;
  }

  const int r0 = tid >> 2;
  const int e0 = (tid & 3) * 8;
  for (int h = 0; h < 16; ++h) {
    const ushort* Kh = Kp + ((size_t)(b * 16 + h) * SS + kblk) * DKK;
    const ushort* Qh = Qp + ((size_t)(b * 16 + h) * SS + qblk) * DKK;
    f32x4 acc[4][4];
    {
      f32x4 z = {0.f, 0.f, 0.f, 0.f};
#pragma unroll
      for (int i = 0; i < 4; ++i)
#pragma unroll
        for (int j = 0; j < 4; ++j) acc[i][j] = z;
    }
#pragma unroll
    for (int dh = 0; dh < 2; ++dh) {
      const int d0 = dh * 32;
#pragma unroll
      for (int it = 0; it < 2; ++it) {
        const int row = r0 + it * 64;
        *(s16x8*)&As[row * 32 + e0] = *(const s16x8*)(Kh + (size_t)row * DKK + d0 + e0);
        *(s16x8*)&Bs[row * 32 + e0] = *(const s16x8*)(Qh + (size_t)row * DKK + d0 + e0);
      }
      __syncthreads();
      s16x8 af[4], bf[4];
#pragma unroll
      for (int t = 0; t < 4; ++t) {
        af[t] = *(const s16x8*)&As[(wr * 64 + t * 16 + q) * 32 + g * 8];
        bf[t] = *(const s16x8*)&Bs[(wc * 64 + t * 16 + q) * 32 + g * 8];
      }
#pragma unroll
      for (int mt = 0; mt < 4; ++mt)
#pragma unroll
        for (int nt = 0; nt < 4; ++nt)
          acc[mt][nt] = MFMA_B16(af[mt], bf[nt], acc[mt][nt]);
      __syncthreads();
    }
#pragma unroll
    for (int mt = 0; mt < 4; ++mt)
#pragma unroll
      for (int nt = 0; nt < 4; ++nt)
#pragma unroll
        for (int r = 0; r < 4; ++r)
          den[mt][nt][r] += __expf(acc[mt][nt][r]);
  }

  // epilogue: transpose 64k x 64q wave tile -> rden[q][k] via swizzled LDS.
  char* aw2 = (char*)smem + wave * 8192;   // 8 KB wave-private
#pragma unroll
  for (int mt = 0; mt < 4; ++mt)
#pragma unroll
    for (int nt = 0; nt < 4; ++nt) {
      const int ql = nt * 16 + q;           // q_local within wave tile
      ushort4 pk;
      pk.x = f2bf(1.0f / den[mt][nt][0]);
      pk.y = f2bf(1.0f / den[mt][nt][1]);
      pk.z = f2bf(1.0f / den[mt][nt][2]);
      pk.w = f2bf(1.0f / den[mt][nt][3]);   // k_local = mt*16+g*4 + 0..3
      *(ushort4*)(aw2 + ql * 128 + ((mt * 32 + g * 8) ^ ((ql & 7) << 4))) = pk;
    }
  // same-wave LDS write->read (lgkmcnt auto), then coalesced stores
#pragma unroll
  for (int it = 0; it < 8; ++it) {
    const int idx = it * 64 + lane;
    const int row = idx >> 3;               // q_local 0..63
    const int seg = idx & 7;                // 16B segment of k
    s16x8 v = *(const s16x8*)(aw2 + row * 128 + ((seg * 16) ^ ((row & 7) << 4)));
    *(s16x8*)(Rden + (size_t)b * SS * SS
              + (size_t)(qblk + wc * 64 + row) * SS
              + kblk + wr * 64 + seg * 8) = v;
  }
}

// ---------------- pass 2: block-tiled attention, 8 waves ----------------
__global__ __launch_bounds__(512, 2) void attn4_kernel(
    const ushort* __restrict__ Qp, const ushort* __restrict__ Kp,
    const ushort* __restrict__ Vt, const ushort* __restrict__ Rden,
    ushort* __restrict__ Ctx)
{
  __shared__ ushort Ktile[64 * 64];      //  8 KB, row k (swz by k&7)
  __shared__ ushort Vtile[64 * 64];      //  8 KB, row dk (swz by dk&7)
  __shared__ ushort Rw_all[8][16 * 64];  // 16 KB, per-wave rden rows (swz)
  __shared__ ushort aw_all[8][16 * 64];  // 16 KB, per-wave P / epilogue

  const int tid  = threadIdx.x;
  const int lane = tid & 63;
  const int w    = tid >> 6;             // wave 0..7
  const int q    = lane & 15;
  const int g    = lane >> 4;
  const int bid  = blockIdx.x;
  const int bh   = bid & 31;
  const int b    = bh >> 4, h = bh & 15;
  const int qblk = (bid >> 5) * 128;

  // hoist Q fragment (B-operand: col=lane&15 -> q-row, dk contiguous per g)
  const ushort* Qb = Qp + ((size_t)bh * SS + qblk + w * 16 + q) * DKK + g * 8;
  s16x8 qf0 = *(const s16x8*)(Qb);
  s16x8 qf1 = *(const s16x8*)(Qb + 32);

  const ushort* Ks = Kp + (size_t)bh * SS * DKK;        // K rows contiguous
  const ushort* Vs = Vt + (size_t)bh * DKK * SS;        // V^T rows stride SS
  const ushort* Rs = Rden + (size_t)b * SS * SS + (size_t)(qblk + w * 16) * SS;

  f32x4 acc[4];
  {
    f32x4 z = {0.f, 0.f, 0.f, 0.f};
#pragma unroll
    for (int n = 0; n < 4; ++n) acc[n] = z;
  }

  ushort* Rw = Rw_all[w];
  ushort* aw = aw_all[w];
  const int srow = tid >> 3, sseg = tid & 7;            // K/V staging coords
  const int sd   = (sseg * 8) ^ ((srow & 7) << 3);
  const int r16  = lane >> 2;                           // R staging row 0..15
  const int sgA  = (lane & 3) * 2;                      // R staging 8u-block base

  for (int kt = 0; kt < 32; ++kt) {
    const int k0 = kt * 64;
    // ---- stage K (contiguous 8KB) + V^T (64 rows x 128B), 16B/thread each
    *(s16x8*)&Ktile[srow * 64 + sd] = *(const s16x8*)(Ks + (size_t)k0 * DKK + tid * 8);
    *(s16x8*)&Vtile[srow * 64 + sd] = *(const s16x8*)(Vs + (size_t)srow * SS + k0 + sseg * 8);
    // ---- stage wave's 16 rden rows (same-wave write->read, no barrier)
#pragma unroll
    for (int it = 0; it < 2; ++it) {
      const int sb = sgA + it;   // 8-ushort block 0..7
      *(s16x8*)&Rw[r16 * 64 + ((sb * 8) ^ ((r16 & 7) << 3))] =
          *(const s16x8*)(Rs + (size_t)r16 * SS + k0 + sb * 8);
    }
    __syncthreads();

    // ---- QK scores -> exp * rden -> P into wave-private aw
#pragma unroll
    for (int ks = 0; ks < 4; ++ks) {
      const int kr = ks * 16 + q;
      s16x8 a0 = *(const s16x8*)&Ktile[kr * 64 + ((g * 8) ^ ((kr & 7) << 3))];
      s16x8 a1 = *(const s16x8*)&Ktile[kr * 64 + ((32 + g * 8) ^ ((kr & 7) << 3))];
      f32x4 c = {0.f, 0.f, 0.f, 0.f};
      c = MFMA_B16(a0, qf0, c);
      c = MFMA_B16(a1, qf1, c);
      // rden[q][ks*16+g*4 .. +3] from swizzled Rw
      ushort4 rv = *(const ushort4*)&Rw[q * 64 + (((ks * 2 + (g >> 1)) ^ (q & 7)) * 8) + (g & 1) * 4];
      uint2 pp;
      pp.x = (uint)f2bf(__expf(c[0]) * bf2f(rv.x)) |
             ((uint)f2bf(__expf(c[1]) * bf2f(rv.y)) << 16);
      pp.y = (uint)f2bf(__expf(c[2]) * bf2f(rv.z)) |
             ((uint)f2bf(__expf(c[3]) * bf2f(rv.w)) << 16);
      *(uint2*)&aw[q * 64 + ((ks * 16 + g * 4) ^ ((q & 7) << 3))] = pp;
    }
    // ---- PV over the 64-key tile (same-wave aw; lgkmcnt auto)
#pragma unroll
    for (int kc = 0; kc < 2; ++kc) {
      s16x8 vf[4];
#pragma unroll
      for (int n = 0; n < 4; ++n) {
        const int vr = n * 16 + q;
        vf[n] = *(const s16x8*)&Vtile[vr * 64 + ((kc * 32 + g * 8) ^ ((vr & 7) << 3))];
      }
      s16x8 pa = *(const s16x8*)&aw[q * 64 + ((kc * 32 + g * 8) ^ ((q & 7) << 3))];
#pragma unroll
      for (int n = 0; n < 4; ++n)
        acc[n] = MFMA_B16(pa, vf[n], acc[n]);
    }
    __syncthreads();
  }

  // epilogue: stage 16 rows x 64 cols in wave-private aw, then coalesced
  // 16B/lane stores (each instr: 8 rows x 128B contiguous).
#pragma unroll
  for (int n = 0; n < 4; ++n)
#pragma unroll
    for (int j = 0; j < 4; ++j)
      aw[(g * 4 + j) * 64 + n * 16 + q] = f2bf(acc[n][j]);
  ushort* P = Ctx + ((size_t)(b * SS) + qblk + w * 16) * DD + h * 64;
#pragma unroll
  for (int it = 0; it < 2; ++it) {
    const int idx = it * 64 + lane;
    const int row = idx >> 3;
    const int seg = idx & 7;
    s16x8 v = *(const s16x8*)&aw[row * 64 + seg * 8];
    *(s16x8*)(P + (size_t)row * DD + seg * 8) = v;
  }
}

extern "C" void kernel_launch(void* const* d_in, const int* in_sizes, int n_in,
                              void* d_out, int out_size, void* d_ws, size_t ws_size,
                              hipStream_t stream) {
  const float* Query = (const float*)d_in[0];
  const float* Key   = (const float*)d_in[1];
  const float* Value = (const float*)d_in[2];
  const float* Wq    = (const float*)d_in[3];
  const float* Wk    = (const float*)d_in[4];
  const float* Wv    = (const float*)d_in[5];
  const float* Wo    = (const float*)d_in[6];

  size_t off = 0;
  char* ws = (char*)d_ws;
  auto alloc = [&](size_t bytes) -> void* {
    void* p = ws + off;
    off += (bytes + 255) & ~(size_t)255;
    return p;
  };
  const size_t nX = (size_t)MM * DD;       // 4194304
  const size_t nW = (size_t)DD * DD;       // 1048576
  const size_t nS = (size_t)BB * SS * SS;  // 8388608
  ushort* Wqb  = (ushort*)alloc(nW * 2);
  ushort* Wkb  = (ushort*)alloc(nW * 2);
  ushort* Wvb  = (ushort*)alloc(nW * 2);
  ushort* Wob  = (ushort*)alloc(nW * 2);
  ushort* Qp   = (ushort*)alloc(nX * 2);
  ushort* Kp   = (ushort*)alloc(nX * 2);
  ushort* Vtb  = (ushort*)alloc(nX * 2);
  ushort* Rden = (ushort*)alloc(nS * 2);   // bf16 1/den, 16.7 MB
  ushort* Ctx  = (ushort*)alloc(nX * 2);

  // weights -> bf16 (16 MB fp32 total, streaming, ~6 us)
  cvt_kernel<<<(int)(nW / 2048), 256, 0, stream>>>(Wq, Wqb, (int)nW);
  cvt_kernel<<<(int)(nW / 2048), 256, 0, stream>>>(Wk, Wkb, (int)nW);
  cvt_kernel<<<(int)(nW / 2048), 256, 0, stream>>>(Wv, Wvb, (int)nW);
  cvt_kernel<<<(int)(nW / 2048), 256, 0, stream>>>(Wo, Wob, (int)nW);

  // fused Q/K/V projections: 768 blocks = 3 blocks/CU
  qkv_proj<<<dim3(32, 8, 3), 256, 0, stream>>>(
      Query, Key, Value, Wqb, Wkb, Wvb, Qp, Kp, Vtb);

  den_kernel<<<dim3(16, 16, 2), 256, 0, stream>>>(Qp, Kp, Rden);
  attn4_kernel<<<512, 512, 0, stream>>>(Qp, Kp, Vtb, Rden, Ctx);

  o_proj<<<dim3(32, 8), 256, 0, stream>>>(Ctx, Wob, (float*)d_out);
}

// Round 12
// 177.334 us; speedup vs baseline: 1.8164x; 1.0600x over previous
//
#include <hip/hip_runtime.h>
#include <stdint.h>

#define BB   2
#define SS   2048
#define DD   1024
#define HH   16
#define DKK  64
#define MM   (BB*SS)   // 4096 rows total

typedef __attribute__((ext_vector_type(4))) float f32x4;
typedef __attribute__((ext_vector_type(8))) short s16x8;

#define MFMA_B16(a, b, c) __builtin_amdgcn_mfma_f32_16x16x32_bf16((a), (b), (c), 0, 0, 0)

__device__ __forceinline__ ushort f2bf(float f) {
  uint u = __float_as_uint(f);
  u += 0x7FFFu + ((u >> 16) & 1u);   // round-to-nearest-even
  return (ushort)(u >> 16);
}
__device__ __forceinline__ float bf2f(ushort u) {
  return __uint_as_float((uint)u << 16);
}
__device__ __forceinline__ s16x8 cvt8(const float* src) {
  float4 a = *(const float4*)src, b = *(const float4*)(src + 4);
  union { ushort u[8]; s16x8 v; } r;
  r.u[0] = f2bf(a.x); r.u[1] = f2bf(a.y); r.u[2] = f2bf(a.z); r.u[3] = f2bf(a.w);
  r.u[4] = f2bf(b.x); r.u[5] = f2bf(b.y); r.u[6] = f2bf(b.z); r.u[7] = f2bf(b.w);
  return r.v;
}

// ---------------- fp32 -> bf16 convert (8 elems/thread) — weights only ----------------
__global__ void cvt_kernel(const float* __restrict__ src, ushort* __restrict__ dst, int n) {
  int i = (blockIdx.x * 256 + threadIdx.x) * 8;
  if (i >= n) return;
  *(s16x8*)(dst + i) = cvt8(src + i);
}

// ---------------- fused Q/K/V projection: z selects proj ----------------
__global__ __launch_bounds__(256, 2) void qkv_proj(
    const float* __restrict__ Ia, const float* __restrict__ Ib, const float* __restrict__ Ic,
    const ushort* __restrict__ Wa, const ushort* __restrict__ Wb, const ushort* __restrict__ Wc,
    ushort* __restrict__ Oa, ushort* __restrict__ Ob, ushort* __restrict__ Oc)
{
  __shared__ ushort As[128 * 32];
  __shared__ ushort Bs[128 * 32];
  const int tid  = threadIdx.x;
  const int lane = tid & 63, wave = tid >> 6;
  const int q = lane & 15, g = lane >> 4;
  const int wr = wave >> 1, wc = wave & 1;
  const int mblk = blockIdx.x * 128, nblk = blockIdx.y * 128;
  const int mode = blockIdx.z;

  const float*  A = (mode == 0) ? Ia : (mode == 1) ? Ib : Ic;
  const ushort* W = (mode == 0) ? Wa : (mode == 1) ? Wb : Wc;

  f32x4 acc[4][4];
  {
    f32x4 z = {0.f, 0.f, 0.f, 0.f};
#pragma unroll
    for (int i = 0; i < 4; ++i)
#pragma unroll
      for (int j = 0; j < 4; ++j) acc[i][j] = z;
  }

  const int r0 = tid >> 2;            // staging row
  const int e0 = (tid & 3) * 8;       // staging element offset within row
  for (int k0 = 0; k0 < 1024; k0 += 32) {
#pragma unroll
    for (int it = 0; it < 2; ++it) {
      const int row = r0 + it * 64;
      *(s16x8*)&As[row * 32 + e0] = cvt8(A + (size_t)(mblk + row) * 1024 + k0 + e0);
      *(s16x8*)&Bs[row * 32 + e0] = *(const s16x8*)(W + (size_t)(nblk + row) * 1024 + k0 + e0);
    }
    __syncthreads();
    s16x8 af[4], bf[4];
#pragma unroll
    for (int t = 0; t < 4; ++t) {
      af[t] = *(const s16x8*)&As[(wr * 64 + t * 16 + q) * 32 + g * 8];
      bf[t] = *(const s16x8*)&Bs[(wc * 64 + t * 16 + q) * 32 + g * 8];
    }
#pragma unroll
    for (int mt = 0; mt < 4; ++mt)
#pragma unroll
      for (int nt = 0; nt < 4; ++nt)
        acc[mt][nt] = MFMA_B16(af[mt], bf[nt], acc[mt][nt]);
    __syncthreads();
  }

  // epilogue (C layout: col = lane&15 (N), row = (lane>>4)*4 + j (M))
  if (mode == 2) {
    ushort* Vt = Oc;
#pragma unroll
    for (int mt = 0; mt < 4; ++mt)
#pragma unroll
      for (int nt = 0; nt < 4; ++nt) {
        const int s0 = mblk + wr * 64 + mt * 16 + g * 4;
        const int o  = nblk + wc * 64 + nt * 16 + q;
        const int h = o >> 6, dk = o & 63;
        const int b = s0 >> 11, sr = s0 & 2047;
        ushort4 pk;
        pk.x = f2bf(acc[mt][nt][0]); pk.y = f2bf(acc[mt][nt][1]);
        pk.z = f2bf(acc[mt][nt][2]); pk.w = f2bf(acc[mt][nt][3]);
        *(ushort4*)(Vt + ((size_t)((b * 16 + h) * 64 + dk)) * SS + sr) = pk;
      }
  } else {
    const float scale = (mode == 0) ? 0.125f : 1.0f;
    ushort* P = (mode == 0) ? Oa : Ob;
    ushort* wl = As + wave * 1024;   // 2KB wave-private staging (reuse As)
    const int h0 = (nblk + wc * 64) >> 6;
#pragma unroll
    for (int mt = 0; mt < 4; ++mt) {
      const int s0 = mblk + wr * 64 + mt * 16;
      const int b  = s0 >> 11, sr0 = s0 & 2047;
#pragma unroll
      for (int nt = 0; nt < 4; ++nt)
#pragma unroll
        for (int j = 0; j < 4; ++j)
          wl[(g * 4 + j) * 64 + nt * 16 + q] = f2bf(acc[mt][nt][j] * scale);
      // same-wave LDS write->read: compiler inserts lgkmcnt wait
#pragma unroll
      for (int it = 0; it < 2; ++it) {
        s16x8 v = *(const s16x8*)((char*)wl + it * 1024 + lane * 16);
        const int lr = it * 8 + (lane >> 3);
        const int c  = (lane & 7) * 8;
        *(s16x8*)(P + ((size_t)((b * 16 + h0) * SS) + sr0 + lr) * DKK + c) = v;
      }
    }
  }
}

// ---------------- O-projection: Y = Ctx @ Wo^T -> fp32 d_out ----------------
__global__ __launch_bounds__(256, 2) void o_proj(
    const ushort* __restrict__ A, const ushort* __restrict__ W,
    float* __restrict__ O)
{
  __shared__ ushort As[128 * 32];
  __shared__ ushort Bs[128 * 32];
  const int tid  = threadIdx.x;
  const int lane = tid & 63, wave = tid >> 6;
  const int q = lane & 15, g = lane >> 4;
  const int wr = wave >> 1, wc = wave & 1;
  const int mblk = blockIdx.x * 128, nblk = blockIdx.y * 128;

  f32x4 acc[4][4];
  {
    f32x4 z = {0.f, 0.f, 0.f, 0.f};
#pragma unroll
    for (int i = 0; i < 4; ++i)
#pragma unroll
      for (int j = 0; j < 4; ++j) acc[i][j] = z;
  }

  const int r0 = tid >> 2;
  const int e0 = (tid & 3) * 8;
  for (int k0 = 0; k0 < 1024; k0 += 32) {
#pragma unroll
    for (int it = 0; it < 2; ++it) {
      const int row = r0 + it * 64;
      *(s16x8*)&As[row * 32 + e0] = *(const s16x8*)(A + (size_t)(mblk + row) * 1024 + k0 + e0);
      *(s16x8*)&Bs[row * 32 + e0] = *(const s16x8*)(W + (size_t)(nblk + row) * 1024 + k0 + e0);
    }
    __syncthreads();
    s16x8 af[4], bf[4];
#pragma unroll
    for (int t = 0; t < 4; ++t) {
      af[t] = *(const s16x8*)&As[(wr * 64 + t * 16 + q) * 32 + g * 8];
      bf[t] = *(const s16x8*)&Bs[(wc * 64 + t * 16 + q) * 32 + g * 8];
    }
#pragma unroll
    for (int mt = 0; mt < 4; ++mt)
#pragma unroll
      for (int nt = 0; nt < 4; ++nt)
        acc[mt][nt] = MFMA_B16(af[mt], bf[nt], acc[mt][nt]);
    __syncthreads();
  }

#pragma unroll
  for (int mt = 0; mt < 4; ++mt)
#pragma unroll
    for (int nt = 0; nt < 4; ++nt)
#pragma unroll
      for (int j = 0; j < 4; ++j) {
        const int s = mblk + wr * 64 + mt * 16 + g * 4 + j;
        const int o = nblk + wc * 64 + nt * 16 + q;
        O[(size_t)s * DD + o] = acc[mt][nt][j];
      }
}

// ---------------- pass 1: rden = 1/sum_h exp(s) — GEMM-shaped, double-buffered ----------------
// Flattened 32 steps (h 0..15 x dh 0..1), LDS double-buffered with T14 split:
// issue next step's 4 global loads at step top, compute current, LDS-write
// staged regs, ONE barrier per step (was 2 per step = 64/block).
__global__ __launch_bounds__(256, 2) void den_kernel(
    const ushort* __restrict__ Qp, const ushort* __restrict__ Kp,
    ushort* __restrict__ Rden)
{
  __shared__ ushort smem[2][8192];      // [buf][As 4096 | Bs 4096] = 32 KB
  const int tid  = threadIdx.x;
  const int lane = tid & 63, wave = tid >> 6;
  const int q = lane & 15, g = lane >> 4;
  const int wr = wave >> 1, wc = wave & 1;
  const int kblk = blockIdx.x * 128, qblk = blockIdx.y * 128;
  const int b = blockIdx.z;

  f32x4 den[4][4], acc[4][4];
  {
    f32x4 z = {0.f, 0.f, 0.f, 0.f};
#pragma unroll
    for (int i = 0; i < 4; ++i)
#pragma unroll
      for (int j = 0; j < 4; ++j) { den[i][j] = z; acc[i][j] = z; }
  }

  const int r0 = tid >> 2;
  const int e0 = (tid & 3) * 8;

  // prologue: stage step 0 (h=0, dh=0) into buf 0
  {
    const ushort* Kh = Kp + ((size_t)(b * 16) * SS + kblk) * DKK;
    const ushort* Qh = Qp + ((size_t)(b * 16) * SS + qblk) * DKK;
    *(s16x8*)&smem[0][r0 * 32 + e0]        = *(const s16x8*)(Kh + (size_t)r0 * DKK + e0);
    *(s16x8*)&smem[0][(r0 + 64) * 32 + e0] = *(const s16x8*)(Kh + (size_t)(r0 + 64) * DKK + e0);
    *(s16x8*)&smem[0][4096 + r0 * 32 + e0]        = *(const s16x8*)(Qh + (size_t)r0 * DKK + e0);
    *(s16x8*)&smem[0][4096 + (r0 + 64) * 32 + e0] = *(const s16x8*)(Qh + (size_t)(r0 + 64) * DKK + e0);
  }
  __syncthreads();

  for (int s = 0; s < 32; ++s) {
    const int cur = s & 1;
    // issue next step's loads (T14: latency hides under compute below)
    s16x8 nA0, nA1, nB0, nB1;
    if (s < 31) {
      const int h1 = (s + 1) >> 1, d1 = ((s + 1) & 1) * 32;
      const ushort* Kh = Kp + ((size_t)(b * 16 + h1) * SS + kblk) * DKK + d1;
      const ushort* Qh = Qp + ((size_t)(b * 16 + h1) * SS + qblk) * DKK + d1;
      nA0 = *(const s16x8*)(Kh + (size_t)r0 * DKK + e0);
      nA1 = *(const s16x8*)(Kh + (size_t)(r0 + 64) * DKK + e0);
      nB0 = *(const s16x8*)(Qh + (size_t)r0 * DKK + e0);
      nB1 = *(const s16x8*)(Qh + (size_t)(r0 + 64) * DKK + e0);
    }
    // compute from smem[cur]
    s16x8 af[4], bf[4];
#pragma unroll
    for (int t = 0; t < 4; ++t) {
      af[t] = *(const s16x8*)&smem[cur][(wr * 64 + t * 16 + q) * 32 + g * 8];
      bf[t] = *(const s16x8*)&smem[cur][4096 + (wc * 64 + t * 16 + q) * 32 + g * 8];
    }
#pragma unroll
    for (int mt = 0; mt < 4; ++mt)
#pragma unroll
      for (int nt = 0; nt < 4; ++nt)
        acc[mt][nt] = MFMA_B16(af[mt], bf[nt], acc[mt][nt]);
    if (s & 1) {   // head complete: accumulate exp, reset acc
      f32x4 z = {0.f, 0.f, 0.f, 0.f};
#pragma unroll
      for (int mt = 0; mt < 4; ++mt)
#pragma unroll
        for (int nt = 0; nt < 4; ++nt) {
#pragma unroll
          for (int r = 0; r < 4; ++r)
            den[mt][nt][r] += __expf(acc[mt][nt][r]);
          acc[mt][nt] = z;
        }
    }
    // write staged regs into the other buffer
    if (s < 31) {
      *(s16x8*)&smem[cur ^ 1][r0 * 32 + e0]        = nA0;
      *(s16x8*)&smem[cur ^ 1][(r0 + 64) * 32 + e0] = nA1;
      *(s16x8*)&smem[cur ^ 1][4096 + r0 * 32 + e0]        = nB0;
      *(s16x8*)&smem[cur ^ 1][4096 + (r0 + 64) * 32 + e0] = nB1;
    }
    __syncthreads();
  }

  // epilogue: transpose 64k x 64q wave tile -> rden[q][k] via swizzled LDS.
  char* aw2 = (char*)smem + wave * 8192;   // 8 KB wave-private
#pragma unroll
  for (int mt = 0; mt < 4; ++mt)
#pragma unroll
    for (int nt = 0; nt < 4; ++nt) {
      const int ql = nt * 16 + q;           // q_local within wave tile
      ushort4 pk;
      pk.x = f2bf(1.0f / den[mt][nt][0]);
      pk.y = f2bf(1.0f / den[mt][nt][1]);
      pk.z = f2bf(1.0f / den[mt][nt][2]);
      pk.w = f2bf(1.0f / den[mt][nt][3]);   // k_local = mt*16+g*4 + 0..3
      *(ushort4*)(aw2 + ql * 128 + ((mt * 32 + g * 8) ^ ((ql & 7) << 4))) = pk;
    }
  // same-wave LDS write->read (lgkmcnt auto), then coalesced stores
#pragma unroll
  for (int it = 0; it < 8; ++it) {
    const int idx = it * 64 + lane;
    const int row = idx >> 3;               // q_local 0..63
    const int seg = idx & 7;                // 16B segment of k
    s16x8 v = *(const s16x8*)(aw2 + row * 128 + ((seg * 16) ^ ((row & 7) << 4)));
    *(s16x8*)(Rden + (size_t)b * SS * SS
              + (size_t)(qblk + wc * 64 + row) * SS
              + kblk + wr * 64 + seg * 8) = v;
  }
}

// ---------------- pass 2: block-tiled attention, double-buffered K/V ----------------
// grid 512, 8 waves.  One barrier per 64-key phase: issue next tile's global
// loads at phase top (T14), compute (QK -> exp*rden -> P -> PV) from current
// buffer, LDS-write staged regs into the other buffer, barrier.  R and P are
// wave-private (same-wave program order -> single-buffered, no barrier).
// P packed with v_cvt_pk_bf16_f32 (2 instrs vs ~20 manual VALU ops per ks).
__global__ __launch_bounds__(512, 2) void attn5_kernel(
    const ushort* __restrict__ Qp, const ushort* __restrict__ Kp,
    const ushort* __restrict__ Vt, const ushort* __restrict__ Rden,
    ushort* __restrict__ Ctx)
{
  __shared__ ushort Ktile[2][64 * 64];   // 16 KB, row k (swz by k&7)
  __shared__ ushort Vtile[2][64 * 64];   // 16 KB, row dk (swz by dk&7)
  __shared__ ushort Rw_all[8][16 * 64];  // 16 KB, per-wave rden rows (swz)
  __shared__ ushort aw_all[8][16 * 64];  // 16 KB, per-wave P / epilogue

  const int tid  = threadIdx.x;
  const int lane = tid & 63;
  const int w    = tid >> 6;             // wave 0..7
  const int q    = lane & 15;
  const int g    = lane >> 4;
  const int bid  = blockIdx.x;
  const int bh   = bid & 31;
  const int b    = bh >> 4, h = bh & 15;
  const int qblk = (bid >> 5) * 128;

  const ushort* Qb = Qp + ((size_t)bh * SS + qblk + w * 16 + q) * DKK + g * 8;
  s16x8 qf0 = *(const s16x8*)(Qb);
  s16x8 qf1 = *(const s16x8*)(Qb + 32);

  const ushort* Ks = Kp + (size_t)bh * SS * DKK;
  const ushort* Vs = Vt + (size_t)bh * DKK * SS;
  const ushort* Rs = Rden + (size_t)b * SS * SS + (size_t)(qblk + w * 16) * SS;

  f32x4 acc[4];
  {
    f32x4 z = {0.f, 0.f, 0.f, 0.f};
#pragma unroll
    for (int n = 0; n < 4; ++n) acc[n] = z;
  }

  ushort* Rw = Rw_all[w];
  ushort* aw = aw_all[w];
  const int srow = tid >> 3, sseg = tid & 7;
  const int sd   = (sseg * 8) ^ ((srow & 7) << 3);
  const int r16  = lane >> 2;
  const int sgA  = (lane & 3) * 2;
  const int rd0  = r16 * 64 + ((sgA * 8) ^ ((r16 & 7) << 3));
  const int rd1  = r16 * 64 + (((sgA + 1) * 8) ^ ((r16 & 7) << 3));

  // prologue: stage phase 0 into buffer 0
  {
    s16x8 gK  = *(const s16x8*)(Ks + tid * 8);
    s16x8 gV  = *(const s16x8*)(Vs + (size_t)srow * SS + sseg * 8);
    s16x8 gR0 = *(const s16x8*)(Rs + (size_t)r16 * SS + sgA * 8);
    s16x8 gR1 = *(const s16x8*)(Rs + (size_t)r16 * SS + (sgA + 1) * 8);
    *(s16x8*)&Ktile[0][srow * 64 + sd] = gK;
    *(s16x8*)&Vtile[0][srow * 64 + sd] = gV;
    *(s16x8*)&Rw[rd0] = gR0;
    *(s16x8*)&Rw[rd1] = gR1;
  }
  __syncthreads();

  for (int kt = 0; kt < 32; ++kt) {
    const int cur = kt & 1;
    // ---- issue next tile's global loads (latency hides under compute)
    s16x8 gK, gV, gR0, gR1;
    if (kt < 31) {
      const int k1 = (kt + 1) * 64;
      gK  = *(const s16x8*)(Ks + (size_t)k1 * DKK + tid * 8);
      gV  = *(const s16x8*)(Vs + (size_t)srow * SS + k1 + sseg * 8);
      gR0 = *(const s16x8*)(Rs + (size_t)r16 * SS + k1 + sgA * 8);
      gR1 = *(const s16x8*)(Rs + (size_t)r16 * SS + k1 + (sgA + 1) * 8);
    }
    const ushort* Kt = Ktile[cur];
    const ushort* Vv = Vtile[cur];

    // ---- QK scores -> exp * rden -> P into wave-private aw
#pragma unroll
    for (int ks = 0; ks < 4; ++ks) {
      const int kr = ks * 16 + q;
      s16x8 a0 = *(const s16x8*)&Kt[kr * 64 + ((g * 8) ^ ((kr & 7) << 3))];
      s16x8 a1 = *(const s16x8*)&Kt[kr * 64 + ((32 + g * 8) ^ ((kr & 7) << 3))];
      f32x4 c = {0.f, 0.f, 0.f, 0.f};
      c = MFMA_B16(a0, qf0, c);
      c = MFMA_B16(a1, qf1, c);
      ushort4 rv = *(const ushort4*)&Rw[q * 64 + (((ks * 2 + (g >> 1)) ^ (q & 7)) * 8) + (g & 1) * 4];
      float p0 = __expf(c[0]) * bf2f(rv.x);
      float p1 = __expf(c[1]) * bf2f(rv.y);
      float p2 = __expf(c[2]) * bf2f(rv.z);
      float p3 = __expf(c[3]) * bf2f(rv.w);
      uint2 pp;
      asm("v_cvt_pk_bf16_f32 %0, %1, %2" : "=v"(pp.x) : "v"(p0), "v"(p1));
      asm("v_cvt_pk_bf16_f32 %0, %1, %2" : "=v"(pp.y) : "v"(p2), "v"(p3));
      *(uint2*)&aw[q * 64 + ((ks * 16 + g * 4) ^ ((q & 7) << 3))] = pp;
    }
    // ---- PV over the 64-key tile (same-wave aw; lgkmcnt auto)
#pragma unroll
    for (int kc = 0; kc < 2; ++kc) {
      s16x8 vf[4];
#pragma unroll
      for (int n = 0; n < 4; ++n) {
        const int vr = n * 16 + q;
        vf[n] = *(const s16x8*)&Vv[vr * 64 + ((kc * 32 + g * 8) ^ ((vr & 7) << 3))];
      }
      s16x8 pa = *(const s16x8*)&aw[q * 64 + ((kc * 32 + g * 8) ^ ((q & 7) << 3))];
#pragma unroll
      for (int n = 0; n < 4; ++n)
        acc[n] = MFMA_B16(pa, vf[n], acc[n]);
    }
    // ---- write staged regs into the other buffer (R: wave-private, in-order)
    if (kt < 31) {
      *(s16x8*)&Ktile[cur ^ 1][srow * 64 + sd] = gK;
      *(s16x8*)&Vtile[cur ^ 1][srow * 64 + sd] = gV;
      *(s16x8*)&Rw[rd0] = gR0;
      *(s16x8*)&Rw[rd1] = gR1;
    }
    __syncthreads();
  }

  // epilogue: stage 16 rows x 64 cols in wave-private aw, then coalesced
  // 16B/lane stores (each instr: 8 rows x 128B contiguous).
#pragma unroll
  for (int n = 0; n < 4; ++n)
#pragma unroll
    for (int j = 0; j < 4; ++j)
      aw[(g * 4 + j) * 64 + n * 16 + q] = f2bf(acc[n][j]);
  ushort* P = Ctx + ((size_t)(b * SS) + qblk + w * 16) * DD + h * 64;
#pragma unroll
  for (int it = 0; it < 2; ++it) {
    const int idx = it * 64 + lane;
    const int row = idx >> 3;
    const int seg = idx & 7;
    s16x8 v = *(const s16x8*)&aw[row * 64 + seg * 8];
    *(s16x8*)(P + (size_t)row * DD + seg * 8) = v;
  }
}

extern "C" void kernel_launch(void* const* d_in, const int* in_sizes, int n_in,
                              void* d_out, int out_size, void* d_ws, size_t ws_size,
                              hipStream_t stream) {
  const float* Query = (const float*)d_in[0];
  const float* Key   = (const float*)d_in[1];
  const float* Value = (const float*)d_in[2];
  const float* Wq    = (const float*)d_in[3];
  const float* Wk    = (const float*)d_in[4];
  const float* Wv    = (const float*)d_in[5];
  const float* Wo    = (const float*)d_in[6];

  size_t off = 0;
  char* ws = (char*)d_ws;
  auto alloc = [&](size_t bytes) -> void* {
    void* p = ws + off;
    off += (bytes + 255) & ~(size_t)255;
    return p;
  };
  const size_t nX = (size_t)MM * DD;       // 4194304
  const size_t nW = (size_t)DD * DD;       // 1048576
  const size_t nS = (size_t)BB * SS * SS;  // 8388608
  ushort* Wqb  = (ushort*)alloc(nW * 2);
  ushort* Wkb  = (ushort*)alloc(nW * 2);
  ushort* Wvb  = (ushort*)alloc(nW * 2);
  ushort* Wob  = (ushort*)alloc(nW * 2);
  ushort* Qp   = (ushort*)alloc(nX * 2);
  ushort* Kp   = (ushort*)alloc(nX * 2);
  ushort* Vtb  = (ushort*)alloc(nX * 2);
  ushort* Rden = (ushort*)alloc(nS * 2);   // bf16 1/den, 16.7 MB
  ushort* Ctx  = (ushort*)alloc(nX * 2);

  // weights -> bf16 (16 MB fp32 total, streaming, ~6 us)
  cvt_kernel<<<(int)(nW / 2048), 256, 0, stream>>>(Wq, Wqb, (int)nW);
  cvt_kernel<<<(int)(nW / 2048), 256, 0, stream>>>(Wk, Wkb, (int)nW);
  cvt_kernel<<<(int)(nW / 2048), 256, 0, stream>>>(Wv, Wvb, (int)nW);
  cvt_kernel<<<(int)(nW / 2048), 256, 0, stream>>>(Wo, Wob, (int)nW);

  // fused Q/K/V projections: 768 blocks = 3 blocks/CU
  qkv_proj<<<dim3(32, 8, 3), 256, 0, stream>>>(
      Query, Key, Value, Wqb, Wkb, Wvb, Qp, Kp, Vtb);

  den_kernel<<<dim3(16, 16, 2), 256, 0, stream>>>(Qp, Kp, Rden);
  attn5_kernel<<<512, 512, 0, stream>>>(Qp, Kp, Vtb, Rden, Ctx);

  o_proj<<<dim3(32, 8), 256, 0, stream>>>(Ctx, Wob, (float*)d_out);
}